// Round 9
// baseline (257.260 us; speedup 1.0000x reference)
//
#include <hip/hip_runtime.h>

#define HW    96
#define NPIX  9216        // 96*96
#define NCH   64          // C
#define INNER 3
#define NDIL  3
#define BB    2           // batch
#define TOTPIX (BB * NPIX)   // 18432

typedef __attribute__((ext_vector_type(8))) short short8;            // 8 bf16
typedef __attribute__((ext_vector_type(8))) unsigned short ushort8;  // 8 bf16 raw
typedef __attribute__((ext_vector_type(4))) float f32x4;

__device__ __forceinline__ ushort f2bf_rne(float f) {
    unsigned u = __float_as_uint(f);
    u += 0x7fffu + ((u >> 16) & 1u);
    return (ushort)(u >> 16);
}
__device__ __forceinline__ float bf2f(ushort u) {
    return __uint_as_float((unsigned)u << 16);
}
// pack hi16(a),hi16(b) -> dword {bf16(b)<<16 | bf16(a)} (trunc; ratio-safe for P)
__device__ __forceinline__ unsigned pack_bf(float lo, float hi) {
    return __builtin_amdgcn_perm(__float_as_uint(hi), __float_as_uint(lo), 0x07060302u);
}

// ---------------------------------------------------------------------------
// Kernel 1: x_red = 1x1 conv (64 -> 3 channels)
// ---------------------------------------------------------------------------
__global__ void k_reduce(const float* __restrict__ x, const float* __restrict__ w_red,
                         const float* __restrict__ b_red, float* __restrict__ xred) {
    int pix = blockIdx.x * blockDim.x + threadIdx.x;
    if (pix >= TOTPIX) return;
    int b = pix / NPIX, n = pix % NPIX;
    float a0 = b_red[0], a1 = b_red[1], a2 = b_red[2];
    const float* xb = x + (size_t)b * NCH * NPIX + n;
    #pragma unroll
    for (int c = 0; c < NCH; ++c) {
        float xv = xb[(size_t)c * NPIX];
        a0 = fmaf(w_red[0 * NCH + c], xv, a0);
        a1 = fmaf(w_red[1 * NCH + c], xv, a1);
        a2 = fmaf(w_red[2 * NCH + c], xv, a2);
    }
    float* xr = xred + (size_t)b * INNER * NPIX + n;
    xr[0 * NPIX] = a0; xr[1 * NPIX] = a1; xr[2 * NPIX] = a2;
}

// ---------------------------------------------------------------------------
// Kernel 2a: features. thread = (pixel, dilation i3). Writes FT[j][pix] bf16,
// j = i3*18 + t*3 + o. Rows 54..63 never written — zero-weighted in k_fuse.
// ---------------------------------------------------------------------------
__global__ __launch_bounds__(256) void
k_feat(const float* __restrict__ xred, const float* __restrict__ w_dil,
       const float* __restrict__ b_dil, ushort* __restrict__ FT) {
    int gid = blockIdx.x * 256 + threadIdx.x;      // 3 * 18432 threads
    int i3 = gid / TOTPIX;                          // wave-uniform
    int pix = gid - i3 * TOTPIX;
    int b = pix / NPIX, n = pix % NPIX;
    int h = n / HW, w = n % HW;
    const float* xr = xred + (size_t)b * INNER * NPIX;
    int d = i3 + 1;

    float co[3] = {b_dil[i3 * 3 + 0], b_dil[i3 * 3 + 1], b_dil[i3 * 3 + 2]};
    #pragma unroll
    for (int ci = 0; ci < 3; ++ci) {
        const float* xo = xr + ci * NPIX;
        #pragma unroll
        for (int kh = 0; kh < 3; ++kh) {
            int hh = h + (kh - 1) * d;
            #pragma unroll
            for (int kw = 0; kw < 3; ++kw) {
                int ww = w + (kw - 1) * d;
                float v = ((unsigned)hh < HW && (unsigned)ww < HW) ? xo[hh * HW + ww] : 0.f;
                #pragma unroll
                for (int o = 0; o < 3; ++o)
                    co[o] = fmaf(w_dil[(9 * i3 + 3 * o + ci) * 9 + kh * 3 + kw], v, co[o]);
            }
        }
    }

    float tf[6][3];
    #pragma unroll
    for (int o = 0; o < 3; ++o) {
        const float* xo = xr + o * NPIX;
        tf[0][o] = xo[h * HW + w];
        tf[1][o] = xo[h * HW + (HW - 1 - w)];
        tf[2][o] = xo[(HW - 1 - h) * HW + w];
        tf[3][o] = xo[w * HW + (HW - 1 - h)];
        tf[4][o] = xo[(HW - 1 - h) * HW + (HW - 1 - w)];
        tf[5][o] = xo[(HW - 1 - w) * HW + h];
    }

    #pragma unroll
    for (int t = 0; t < 6; ++t)
        #pragma unroll
        for (int o = 0; o < 3; ++o) {
            int j = i3 * 18 + t * 3 + o;
            FT[(size_t)j * TOTPIX + pix] = f2bf_rne(co[o] * tf[t][o]);
        }
}

// ---------------------------------------------------------------------------
// Kernel 2b: fuse conv as MFMA GEMM, 64 px/block (grid 288).
// ---------------------------------------------------------------------------
__global__ __launch_bounds__(256) void
k_fuse(const ushort* __restrict__ FT, const float* __restrict__ w_fuse,
       const float* __restrict__ b_fuse, ushort* __restrict__ tok,
       ushort* __restrict__ tokT) {
    __shared__ ushort wpad[64 * 72];     // [c][j pad 72]
    __shared__ float  bsh[64];
    __shared__ ushort tile[64 * 72];     // [c][64 px + 8 pad]

    int tid = threadIdx.x;
    for (int i = tid; i < 64 * 64; i += 256) {
        int c = i >> 6, j = i & 63;
        wpad[c * 72 + j] = (j < 54) ? f2bf_rne(w_fuse[c * 54 + j]) : (ushort)0;
    }
    if (tid < 64) bsh[tid] = b_fuse[tid];
    __syncthreads();

    int wv = tid >> 6, lane = tid & 63, quad = lane >> 4, l15 = lane & 15;
    int px0 = blockIdx.x * 64;

    short8 af[4][2];
    #pragma unroll
    for (int m = 0; m < 4; ++m)
        #pragma unroll
        for (int kc = 0; kc < 2; ++kc)
            af[m][kc] = *(const short8*)&wpad[(16 * m + l15) * 72 + quad * 8 + 32 * kc];

    f32x4 acc[4];
    #pragma unroll
    for (int m = 0; m < 4; ++m) acc[m] = (f32x4){0.f, 0.f, 0.f, 0.f};

    int px = px0 + wv * 16 + l15;
    #pragma unroll
    for (int kc = 0; kc < 2; ++kc) {
        short8 bf;
        #pragma unroll
        for (int jj = 0; jj < 8; ++jj)
            bf[jj] = (short)FT[(size_t)(quad * 8 + jj + 32 * kc) * TOTPIX + px];
        #pragma unroll
        for (int m = 0; m < 4; ++m)
            acc[m] = __builtin_amdgcn_mfma_f32_16x16x32_bf16(af[m][kc], bf, acc[m], 0, 0, 0);
    }

    #pragma unroll
    for (int m = 0; m < 4; ++m)
        #pragma unroll
        for (int r = 0; r < 4; ++r) {
            int c = 16 * m + quad * 4 + r;
            tile[c * 72 + wv * 16 + l15] = f2bf_rne(acc[m][r] + bsh[c]);
        }
    __syncthreads();

    int b0 = px0 / NPIX, n0 = px0 % NPIX;
    {   // tok[b][n][c]
        int lp = tid >> 2, part = tid & 3;
        ushort row[16];
        #pragma unroll
        for (int k = 0; k < 16; ++k) row[k] = tile[(part * 16 + k) * 72 + lp];
        ushort* dst = tok + ((size_t)b0 * NPIX + n0 + lp) * NCH + part * 16;
        *(ushort8*)&dst[0] = *(const ushort8*)&row[0];
        *(ushort8*)&dst[8] = *(const ushort8*)&row[8];
    }
    {   // tokT[b][c][n]
        int c = tid >> 2, seg = tid & 3;
        ushort* dst = tokT + ((size_t)b0 * NCH + c) * NPIX + n0 + seg * 16;
        *(ushort8*)&dst[0] = *(const ushort8*)&tile[c * 72 + seg * 16];
        *(ushort8*)&dst[8] = *(const ushort8*)&tile[c * 72 + seg * 16 + 8];
    }
}

// ---------------------------------------------------------------------------
// Kernel 3: MFMA flash attention. Hybrid: BLOCK-shared LDS staging of K/V^T
// (4 waves share each fetch; XOR-chunk swizzle) + per-n softmax (S stays 8
// regs; fixed exp2 base FM, shift-invariant, no max/rescale). pt per-wave
// [16 q][32 k + 8 pad]. Liveness ~148 regs -> launch_bounds(256,3), 12 w/CU.
// pacc written bf16 in [b][p][c][n] layout (32B-sector aligned scalar stores)
// so k_combine reads coalesced.
// ---------------------------------------------------------------------------
__global__ __launch_bounds__(256, 3) void
k_attn(const ushort* __restrict__ tok, const ushort* __restrict__ tokT,
       float* __restrict__ pl, ushort* __restrict__ pacc, int P, int KP) {
    __shared__ ushort kt[64 * 64];      // [key][ch]  8 KB, chunk-XOR swizzle
    __shared__ ushort vt[64 * 64];      // [ch][key]  8 KB, chunk-XOR swizzle
    __shared__ ushort pt[4][16 * 40];   // per-wave P^T [q16][32k + 8 pad], 5 KB

    const int QW = NPIX / 256;          // 36 query chunks per batch
    int bid = blockIdx.x;
    int qc = bid % QW; int rest = bid / QW;
    int p = rest % P;  int b = rest / P;
    int tid = threadIdx.x;
    int wv = tid >> 6, lane = tid & 63;
    int quad = lane >> 4, l15 = lane & 15;

    const ushort* tb  = tok  + (size_t)b * NPIX * NCH;
    const ushort* tbT = tokT + (size_t)b * NCH * NPIX;
    int qwave = qc * 256 + wv * 64;

    // Q fragments: B operand of S^T (lane n=l15, k=quad*8+j+32kc); scale folded.
    short8 qf[4][2];
    const float scale = 0.125f * 1.44269504088896340736f;  // 1/sqrt(C) * log2(e)
    #pragma unroll
    for (int n = 0; n < 4; ++n) {
        const ushort* qr = tb + (size_t)(qwave + 16 * n + l15) * NCH + quad * 8;
        #pragma unroll
        for (int kc = 0; kc < 2; ++kc) {
            ushort8 raw = *(const ushort8*)(qr + 32 * kc);
            short8 f;
            #pragma unroll
            for (int e = 0; e < 8; ++e) f[e] = (short)f2bf_rne(bf2f(raw[e]) * scale);
            qf[n][kc] = f;
        }
    }

    f32x4 O[4][4];                      // O^T acc: D[c=16m+quad*4+reg][q=16n+l15]
    #pragma unroll
    for (int m = 0; m < 4; ++m)
        #pragma unroll
        for (int n = 0; n < 4; ++n) O[m][n] = (f32x4){0.f, 0.f, 0.f, 0.f};
    float lrun[4] = {0.f, 0.f, 0.f, 0.f};

    const float FM = 16.0f;             // fixed exp2-domain shift

    int k0 = p * KP;
    for (int kt0 = 0; kt0 < KP; kt0 += 64) {
        __syncthreads();                // all waves done with previous kt/vt
        #pragma unroll
        for (int ci = tid; ci < 512; ci += 256) {        // stage K [key][ch]
            int row = ci >> 3, cc = ci & 7;
            ushort8 v = *(const ushort8*)(tb + (size_t)(k0 + kt0 + row) * NCH + cc * 8);
            *(ushort8*)&kt[row * 64 + ((cc ^ (row & 7)) * 8)] = v;
        }
        #pragma unroll
        for (int ci = tid; ci < 512; ci += 256) {        // stage V^T [ch][key]
            int row = ci >> 3, cc = ci & 7;
            ushort8 v = *(const ushort8*)(tbT + (size_t)row * NPIX + k0 + kt0 + cc * 8);
            *(ushort8*)&vt[row * 64 + ((cc ^ (row & 7)) * 8)] = v;
        }
        __syncthreads();

        #pragma unroll
        for (int hf = 0; hf < 2; ++hf) {                 // two 32-key halves
            // K fragments from LDS: A[key][ch], rows 32hf..32hf+31
            short8 kf[2][2];
            #pragma unroll
            for (int m2 = 0; m2 < 2; ++m2) {
                int row = 32 * hf + 16 * m2 + l15;
                kf[m2][0] = *(const short8*)&kt[row * 64 + ((quad ^ (row & 7)) * 8)];
                kf[m2][1] = *(const short8*)&kt[row * 64 + (((quad + 4) ^ (row & 7)) * 8)];
            }
            // V^T fragments from LDS: A[ch][key], keys 32hf..+31
            short8 vf[4];
            #pragma unroll
            for (int mc = 0; mc < 4; ++mc) {
                int ch = 16 * mc + l15;
                vf[mc] = *(const short8*)&vt[ch * 64 + (((4 * hf + quad) ^ (ch & 7)) * 8)];
            }

            #pragma unroll
            for (int n = 0; n < 4; ++n) {
                f32x4 s0 = (f32x4){0.f, 0.f, 0.f, 0.f};
                f32x4 s1 = (f32x4){0.f, 0.f, 0.f, 0.f};
                s0 = __builtin_amdgcn_mfma_f32_16x16x32_bf16(kf[0][0], qf[n][0], s0, 0, 0, 0);
                s0 = __builtin_amdgcn_mfma_f32_16x16x32_bf16(kf[0][1], qf[n][1], s0, 0, 0, 0);
                s1 = __builtin_amdgcn_mfma_f32_16x16x32_bf16(kf[1][0], qf[n][0], s1, 0, 0, 0);
                s1 = __builtin_amdgcn_mfma_f32_16x16x32_bf16(kf[1][1], qf[n][1], s1, 0, 0, 0);

                float p0 = __builtin_amdgcn_exp2f(s0[0] - FM);
                float p1 = __builtin_amdgcn_exp2f(s0[1] - FM);
                float p2 = __builtin_amdgcn_exp2f(s0[2] - FM);
                float p3 = __builtin_amdgcn_exp2f(s0[3] - FM);
                float p4 = __builtin_amdgcn_exp2f(s1[0] - FM);
                float p5 = __builtin_amdgcn_exp2f(s1[1] - FM);
                float p6 = __builtin_amdgcn_exp2f(s1[2] - FM);
                float p7 = __builtin_amdgcn_exp2f(s1[3] - FM);
                lrun[n] += ((p0 + p1) + (p2 + p3)) + ((p4 + p5) + (p6 + p7));
                *(uint2*)&pt[wv][l15 * 40 + quad * 4]      = make_uint2(pack_bf(p0, p1), pack_bf(p2, p3));
                *(uint2*)&pt[wv][l15 * 40 + 16 + quad * 4] = make_uint2(pack_bf(p4, p5), pack_bf(p6, p7));

                short8 bfr = *(const short8*)&pt[wv][l15 * 40 + quad * 8];
                #pragma unroll
                for (int mc = 0; mc < 4; ++mc)
                    O[mc][n] = __builtin_amdgcn_mfma_f32_16x16x32_bf16(vf[mc], bfr,
                                                                       O[mc][n], 0, 0, 0);
            }
        }
    }

    #pragma unroll
    for (int n = 0; n < 4; ++n) {       // disjoint key subsets per quad
        lrun[n] += __shfl_xor(lrun[n], 16, 64);
        lrun[n] += __shfl_xor(lrun[n], 32, 64);
    }
    size_t bp = (size_t)b * P + p;
    if (quad == 0) {
        #pragma unroll
        for (int n = 0; n < 4; ++n)
            pl[bp * NPIX + qwave + 16 * n + l15] = lrun[n];
    }
    // pacc[b][p][c][n] layout: per (n,m,r) store 4 c-rows x 32B segments
    #pragma unroll
    for (int n = 0; n < 4; ++n) {
        int qg = qwave + 16 * n + l15;
        #pragma unroll
        for (int m = 0; m < 4; ++m) {
            #pragma unroll
            for (int r = 0; r < 4; ++r) {
                int c = 16 * m + quad * 4 + r;
                pacc[(bp * NCH + c) * NPIX + qg] = f2bf_rne(O[m][n][r]);
            }
        }
    }
}

// ---------------------------------------------------------------------------
// Kernel 3b: Linv[b][n] = 0.2 / sum_p pl[b][p][n]
// ---------------------------------------------------------------------------
__global__ void k_norm(const float* __restrict__ pl, float* __restrict__ linv, int P) {
    int idx = blockIdx.x * blockDim.x + threadIdx.x;
    if (idx >= TOTPIX) return;
    int b = idx / NPIX, n = idx % NPIX;
    float L = 0.f;
    for (int p = 0; p < P; ++p) L += pl[((size_t)b * P + p) * NPIX + n];
    linv[idx] = 0.2f / L;
}

// ---------------------------------------------------------------------------
// Kernel 4: fully-coalesced combine. thread = (b, c, 8-n segment):
// o[n] = sum_p pacc[b][p][c][n] (ushort8 rows), out = x + Linv[n]*o[n].
// ---------------------------------------------------------------------------
__global__ void k_combine(const float* __restrict__ x, const float* __restrict__ linv,
                          const ushort* __restrict__ pacc, float* __restrict__ out,
                          int P) {
    int gid = blockIdx.x * blockDim.x + threadIdx.x;   // (b*NCH + c)*1152 + seg
    if (gid >= BB * NCH * (NPIX / 8)) return;
    int seg = gid % (NPIX / 8);
    int bc  = gid / (NPIX / 8);
    int b = bc / NCH;
    int n0 = seg * 8;
    float o[8] = {0.f, 0.f, 0.f, 0.f, 0.f, 0.f, 0.f, 0.f};
    for (int p = 0; p < P; ++p) {
        ushort8 t = *(const ushort8*)(pacc +
            (((size_t)b * P + p) * NCH + (bc % NCH)) * NPIX + n0);
        #pragma unroll
        for (int e = 0; e < 8; ++e) o[e] += bf2f(t[e]);
    }
    const float* lv = linv + (size_t)b * NPIX + n0;
    const float* xb = x + (size_t)bc * NPIX + n0;
    float* ob = out + (size_t)bc * NPIX + n0;
    #pragma unroll
    for (int e = 0; e < 8; ++e)
        ob[e] = fmaf(lv[e], o[e], xb[e]);
}

// ---------------------------------------------------------------------------
extern "C" void kernel_launch(void* const* d_in, const int* in_sizes, int n_in,
                              void* d_out, int out_size, void* d_ws, size_t ws_size,
                              hipStream_t stream) {
    const float* x      = (const float*)d_in[0];
    const float* w_red  = (const float*)d_in[1];
    const float* b_red  = (const float*)d_in[2];
    const float* w_dil  = (const float*)d_in[3];
    const float* b_dil  = (const float*)d_in[4];
    const float* w_fuse = (const float*)d_in[5];
    const float* b_fuse = (const float*)d_in[6];
    float* out = (float*)d_out;

    // ws: xred f32 | FT bf16 | tok bf16 | tokT bf16 | pl f32 | linv f32 | pacc bf16
    const size_t XRED_N = (size_t)BB * INNER * NPIX;
    const size_t FT_N   = (size_t)64 * TOTPIX;
    const size_t TOK_N  = (size_t)BB * NPIX * NCH;
    const size_t HEAD_B = XRED_N * 4 + (FT_N + 2 * TOK_N) * 2 + TOTPIX * 4;
    int P = 0;
    const int cands[5] = {16, 8, 4, 2, 1};   // KP = 9216/P multiple of 64 for all
    for (int ci = 0; ci < 5; ++ci) {
        int cp = cands[ci];
        size_t need = HEAD_B + (size_t)BB * cp * NPIX * (4 + NCH * 2);
        if (ws_size >= need) { P = cp; break; }
    }
    if (P == 0) return;

    float*  xred = (float*)d_ws;
    ushort* FT   = (ushort*)(xred + XRED_N);
    ushort* tok  = FT + FT_N;
    ushort* tokT = tok + TOK_N;
    float*  pl   = (float*)(tokT + TOK_N);
    float*  linv = pl + (size_t)BB * P * NPIX;
    ushort* pacc = (ushort*)(linv + TOTPIX);

    k_reduce <<<(TOTPIX + 255) / 256, 256, 0, stream>>>(x, w_red, b_red, xred);
    k_feat   <<<3 * TOTPIX / 256, 256, 0, stream>>>(xred, w_dil, b_dil, FT);
    k_fuse   <<<TOTPIX / 64, 256, 0, stream>>>(FT, w_fuse, b_fuse, tok, tokT);
    k_attn   <<<BB * P * (NPIX / 256), 256, 0, stream>>>(tok, tokT, pl, pacc,
                                                         P, NPIX / P);
    k_norm   <<<(TOTPIX + 255) / 256, 256, 0, stream>>>(pl, linv, P);
    k_combine<<<(BB * NCH * (NPIX / 8) + 255) / 256, 256, 0, stream>>>(x, linv, pacc,
                                                                       out, P);
}

// Round 10
// 186.594 us; speedup vs baseline: 1.3787x; 1.3787x over previous
//
#include <hip/hip_runtime.h>

#define HW    96
#define NPIX  9216        // 96*96
#define NCH   64          // C
#define INNER 3
#define NDIL  3
#define BB    2           // batch
#define TOTPIX (BB * NPIX)   // 18432

typedef __attribute__((ext_vector_type(8))) short short8;            // 8 bf16
typedef __attribute__((ext_vector_type(8))) unsigned short ushort8;  // 8 bf16 raw
typedef __attribute__((ext_vector_type(4))) float f32x4;

__device__ __forceinline__ ushort f2bf_rne(float f) {
    unsigned u = __float_as_uint(f);
    u += 0x7fffu + ((u >> 16) & 1u);
    return (ushort)(u >> 16);
}
__device__ __forceinline__ float bf2f(ushort u) {
    return __uint_as_float((unsigned)u << 16);
}
// pack hi16(a),hi16(b) -> dword {bf16(b)<<16 | bf16(a)} (trunc; ratio-safe for P)
__device__ __forceinline__ unsigned pack_bf(float lo, float hi) {
    return __builtin_amdgcn_perm(__float_as_uint(hi), __float_as_uint(lo), 0x07060302u);
}

// ---------------------------------------------------------------------------
// Kernel 1: x_red = 1x1 conv (64 -> 3 channels)
// ---------------------------------------------------------------------------
__global__ void k_reduce(const float* __restrict__ x, const float* __restrict__ w_red,
                         const float* __restrict__ b_red, float* __restrict__ xred) {
    int pix = blockIdx.x * blockDim.x + threadIdx.x;
    if (pix >= TOTPIX) return;
    int b = pix / NPIX, n = pix % NPIX;
    float a0 = b_red[0], a1 = b_red[1], a2 = b_red[2];
    const float* xb = x + (size_t)b * NCH * NPIX + n;
    #pragma unroll
    for (int c = 0; c < NCH; ++c) {
        float xv = xb[(size_t)c * NPIX];
        a0 = fmaf(w_red[0 * NCH + c], xv, a0);
        a1 = fmaf(w_red[1 * NCH + c], xv, a1);
        a2 = fmaf(w_red[2 * NCH + c], xv, a2);
    }
    float* xr = xred + (size_t)b * INNER * NPIX + n;
    xr[0 * NPIX] = a0; xr[1 * NPIX] = a1; xr[2 * NPIX] = a2;
}

// ---------------------------------------------------------------------------
// Kernel 2a: features. thread = (pixel, dilation i3). Writes FT[j][pix] bf16,
// j = i3*18 + t*3 + o. Rows 54..63 never written — zero-weighted in k_fuse.
// ---------------------------------------------------------------------------
__global__ __launch_bounds__(256) void
k_feat(const float* __restrict__ xred, const float* __restrict__ w_dil,
       const float* __restrict__ b_dil, ushort* __restrict__ FT) {
    int gid = blockIdx.x * 256 + threadIdx.x;      // 3 * 18432 threads
    int i3 = gid / TOTPIX;                          // wave-uniform
    int pix = gid - i3 * TOTPIX;
    int b = pix / NPIX, n = pix % NPIX;
    int h = n / HW, w = n % HW;
    const float* xr = xred + (size_t)b * INNER * NPIX;
    int d = i3 + 1;

    float co[3] = {b_dil[i3 * 3 + 0], b_dil[i3 * 3 + 1], b_dil[i3 * 3 + 2]};
    #pragma unroll
    for (int ci = 0; ci < 3; ++ci) {
        const float* xo = xr + ci * NPIX;
        #pragma unroll
        for (int kh = 0; kh < 3; ++kh) {
            int hh = h + (kh - 1) * d;
            #pragma unroll
            for (int kw = 0; kw < 3; ++kw) {
                int ww = w + (kw - 1) * d;
                float v = ((unsigned)hh < HW && (unsigned)ww < HW) ? xo[hh * HW + ww] : 0.f;
                #pragma unroll
                for (int o = 0; o < 3; ++o)
                    co[o] = fmaf(w_dil[(9 * i3 + 3 * o + ci) * 9 + kh * 3 + kw], v, co[o]);
            }
        }
    }

    float tf[6][3];
    #pragma unroll
    for (int o = 0; o < 3; ++o) {
        const float* xo = xr + o * NPIX;
        tf[0][o] = xo[h * HW + w];
        tf[1][o] = xo[h * HW + (HW - 1 - w)];
        tf[2][o] = xo[(HW - 1 - h) * HW + w];
        tf[3][o] = xo[w * HW + (HW - 1 - h)];
        tf[4][o] = xo[(HW - 1 - h) * HW + (HW - 1 - w)];
        tf[5][o] = xo[(HW - 1 - w) * HW + h];
    }

    #pragma unroll
    for (int t = 0; t < 6; ++t)
        #pragma unroll
        for (int o = 0; o < 3; ++o) {
            int j = i3 * 18 + t * 3 + o;
            FT[(size_t)j * TOTPIX + pix] = f2bf_rne(co[o] * tf[t][o]);
        }
}

// ---------------------------------------------------------------------------
// Kernel 2b: fuse conv as MFMA GEMM, 64 px/block (grid 288).
// ---------------------------------------------------------------------------
__global__ __launch_bounds__(256) void
k_fuse(const ushort* __restrict__ FT, const float* __restrict__ w_fuse,
       const float* __restrict__ b_fuse, ushort* __restrict__ tok,
       ushort* __restrict__ tokT) {
    __shared__ ushort wpad[64 * 72];     // [c][j pad 72]
    __shared__ float  bsh[64];
    __shared__ ushort tile[64 * 72];     // [c][64 px + 8 pad]

    int tid = threadIdx.x;
    for (int i = tid; i < 64 * 64; i += 256) {
        int c = i >> 6, j = i & 63;
        wpad[c * 72 + j] = (j < 54) ? f2bf_rne(w_fuse[c * 54 + j]) : (ushort)0;
    }
    if (tid < 64) bsh[tid] = b_fuse[tid];
    __syncthreads();

    int wv = tid >> 6, lane = tid & 63, quad = lane >> 4, l15 = lane & 15;
    int px0 = blockIdx.x * 64;

    short8 af[4][2];
    #pragma unroll
    for (int m = 0; m < 4; ++m)
        #pragma unroll
        for (int kc = 0; kc < 2; ++kc)
            af[m][kc] = *(const short8*)&wpad[(16 * m + l15) * 72 + quad * 8 + 32 * kc];

    f32x4 acc[4];
    #pragma unroll
    for (int m = 0; m < 4; ++m) acc[m] = (f32x4){0.f, 0.f, 0.f, 0.f};

    int px = px0 + wv * 16 + l15;
    #pragma unroll
    for (int kc = 0; kc < 2; ++kc) {
        short8 bf;
        #pragma unroll
        for (int jj = 0; jj < 8; ++jj)
            bf[jj] = (short)FT[(size_t)(quad * 8 + jj + 32 * kc) * TOTPIX + px];
        #pragma unroll
        for (int m = 0; m < 4; ++m)
            acc[m] = __builtin_amdgcn_mfma_f32_16x16x32_bf16(af[m][kc], bf, acc[m], 0, 0, 0);
    }

    #pragma unroll
    for (int m = 0; m < 4; ++m)
        #pragma unroll
        for (int r = 0; r < 4; ++r) {
            int c = 16 * m + quad * 4 + r;
            tile[c * 72 + wv * 16 + l15] = f2bf_rne(acc[m][r] + bsh[c]);
        }
    __syncthreads();

    int b0 = px0 / NPIX, n0 = px0 % NPIX;
    {   // tok[b][n][c]
        int lp = tid >> 2, part = tid & 3;
        ushort row[16];
        #pragma unroll
        for (int k = 0; k < 16; ++k) row[k] = tile[(part * 16 + k) * 72 + lp];
        ushort* dst = tok + ((size_t)b0 * NPIX + n0 + lp) * NCH + part * 16;
        *(ushort8*)&dst[0] = *(const ushort8*)&row[0];
        *(ushort8*)&dst[8] = *(const ushort8*)&row[8];
    }
    {   // tokT[b][c][n]
        int c = tid >> 2, seg = tid & 3;
        ushort* dst = tokT + ((size_t)b0 * NCH + c) * NPIX + n0 + seg * 16;
        *(ushort8*)&dst[0] = *(const ushort8*)&tile[c * 72 + seg * 16];
        *(ushort8*)&dst[8] = *(const ushort8*)&tile[c * 72 + seg * 16 + 8];
    }
}

// ---------------------------------------------------------------------------
// Kernel 3: MFMA flash attention — R6 structure verbatim (known 104 µs, no
// spill): NO LDS staging, NO barriers, K/V^T fragments direct from global
// (token state L1/L2-resident). Monolithic 32-key step: S[2][4] computed by
// 8 MFMA, fixed exp2 base FM (shift-invariant softmax; no max/rescale), pt
// per-wave [64][40] (80B rows), 4 O-MFMAs per 16-query group. launch_bounds
// (256,3). ONLY change vs R6: epilogue writes pacc in [b][p][c][n] layout
// (32B lane-segments) so k_combine reads coalesced.
// ---------------------------------------------------------------------------
__global__ __launch_bounds__(256, 3) void
k_attn(const ushort* __restrict__ tok, const ushort* __restrict__ tokT,
       float* __restrict__ pl, ushort* __restrict__ pacc, int P, int KP) {
    __shared__ ushort pt[4][64 * 40];   // per-wave P^T [q][32key + 8 pad], 20 KB

    const int QW = NPIX / 256;          // 36 query chunks per batch
    int bid = blockIdx.x;
    int qc = bid % QW; int rest = bid / QW;
    int p = rest % P;  int b = rest / P;
    int tid = threadIdx.x;
    int wv = tid >> 6, lane = tid & 63;
    int quad = lane >> 4, l15 = lane & 15;

    const ushort* tb  = tok  + (size_t)b * NPIX * NCH;
    const ushort* tbT = tokT + (size_t)b * NCH * NPIX;
    int qwave = qc * 256 + wv * 64;

    // Q fragments: B operand of S^T (lane n=l15, k=quad*8+j+32kc); scale folded.
    short8 qf[4][2];
    const float scale = 0.125f * 1.44269504088896340736f;  // 1/sqrt(C) * log2(e)
    #pragma unroll
    for (int n = 0; n < 4; ++n) {
        const ushort* qr = tb + (size_t)(qwave + 16 * n + l15) * NCH + quad * 8;
        #pragma unroll
        for (int kc = 0; kc < 2; ++kc) {
            ushort8 raw = *(const ushort8*)(qr + 32 * kc);
            short8 f;
            #pragma unroll
            for (int e = 0; e < 8; ++e) f[e] = (short)f2bf_rne(bf2f(raw[e]) * scale);
            qf[n][kc] = f;
        }
    }

    f32x4 O[4][4];                      // O^T acc: D[c=16m+quad*4+reg][q=16n+l15]
    #pragma unroll
    for (int m = 0; m < 4; ++m)
        #pragma unroll
        for (int n = 0; n < 4; ++n) O[m][n] = (f32x4){0.f, 0.f, 0.f, 0.f};
    float lrun[4] = {0.f, 0.f, 0.f, 0.f};

    const float FM = 16.0f;             // fixed exp2-domain shift

    int k0 = p * KP;
    for (int kb = 0; kb < KP; kb += 32) {
        int kbase = k0 + kb;

        // S^T 32-key step: D[key][q]; A rows (keys) direct from tok
        f32x4 S[2][4];
        #pragma unroll
        for (int m = 0; m < 2; ++m)
            #pragma unroll
            for (int n = 0; n < 4; ++n) S[m][n] = (f32x4){0.f, 0.f, 0.f, 0.f};
        #pragma unroll
        for (int m2 = 0; m2 < 2; ++m2) {
            const ushort* kr = tb + (size_t)(kbase + 16 * m2 + l15) * NCH + quad * 8;
            #pragma unroll
            for (int kc = 0; kc < 2; ++kc) {
                short8 kf = *(const short8*)(kr + 32 * kc);
                #pragma unroll
                for (int n = 0; n < 4; ++n)
                    S[m2][n] = __builtin_amdgcn_mfma_f32_16x16x32_bf16(kf, qf[n][kc],
                                                                       S[m2][n], 0, 0, 0);
            }
        }

        // V^T fragments (A[ch][key]) direct from tokT
        short8 vf[4];
        #pragma unroll
        for (int mc = 0; mc < 4; ++mc)
            vf[mc] = *(const short8*)(tbT + (size_t)(16 * mc + l15) * NPIX + kbase + quad * 8);

        // softmax numerators, fixed base: p = exp2(s - FM)
        #pragma unroll
        for (int n = 0; n < 4; ++n) {
            int q = 16 * n + l15;
            #pragma unroll
            for (int m2 = 0; m2 < 2; ++m2) {
                float p0 = __builtin_amdgcn_exp2f(S[m2][n][0] - FM);
                float p1 = __builtin_amdgcn_exp2f(S[m2][n][1] - FM);
                float p2 = __builtin_amdgcn_exp2f(S[m2][n][2] - FM);
                float p3 = __builtin_amdgcn_exp2f(S[m2][n][3] - FM);
                lrun[n] += (p0 + p1) + (p2 + p3);
                uint2 wd = make_uint2(pack_bf(p0, p1), pack_bf(p2, p3));
                // key_local = 16*m2 + quad*4 + reg
                *(uint2*)&pt[wv][q * 40 + m2 * 16 + quad * 4] = wd;
            }

            // O^T += V^T·P^T (K=32): B[k=quad*8+j][n=q] from padded pt (same wave)
            short8 bfr = *(const short8*)&pt[wv][q * 40 + quad * 8];
            #pragma unroll
            for (int mc = 0; mc < 4; ++mc)
                O[mc][n] = __builtin_amdgcn_mfma_f32_16x16x32_bf16(vf[mc], bfr,
                                                                   O[mc][n], 0, 0, 0);
        }
    }

    #pragma unroll
    for (int n = 0; n < 4; ++n) {       // disjoint key subsets per quad
        lrun[n] += __shfl_xor(lrun[n], 16, 64);
        lrun[n] += __shfl_xor(lrun[n], 32, 64);
    }
    size_t bp = (size_t)b * P + p;
    if (quad == 0) {
        #pragma unroll
        for (int n = 0; n < 4; ++n)
            pl[bp * NPIX + qwave + 16 * n + l15] = lrun[n];
    }
    // pacc[b][p][c][n]: per (n,m,r) scalar 2B stores; across l15 lanes each
    // (m,r) is a 32B contiguous segment -> sector-aligned.
    #pragma unroll
    for (int n = 0; n < 4; ++n) {
        int qg = qwave + 16 * n + l15;
        #pragma unroll
        for (int m = 0; m < 4; ++m) {
            #pragma unroll
            for (int r = 0; r < 4; ++r) {
                int c = 16 * m + quad * 4 + r;
                pacc[(bp * NCH + c) * NPIX + qg] = f2bf_rne(O[m][n][r]);
            }
        }
    }
}

// ---------------------------------------------------------------------------
// Kernel 3b: Linv[b][n] = 0.2 / sum_p pl[b][p][n]
// ---------------------------------------------------------------------------
__global__ void k_norm(const float* __restrict__ pl, float* __restrict__ linv, int P) {
    int idx = blockIdx.x * blockDim.x + threadIdx.x;
    if (idx >= TOTPIX) return;
    int b = idx / NPIX, n = idx % NPIX;
    float L = 0.f;
    for (int p = 0; p < P; ++p) L += pl[((size_t)b * P + p) * NPIX + n];
    linv[idx] = 0.2f / L;
}

// ---------------------------------------------------------------------------
// Kernel 4: fully-coalesced combine. thread = (b, c, 8-n segment):
// o[n] = sum_p pacc[b][p][c][n] (ushort8 rows), out = x + Linv[n]*o[n].
// ---------------------------------------------------------------------------
__global__ void k_combine(const float* __restrict__ x, const float* __restrict__ linv,
                          const ushort* __restrict__ pacc, float* __restrict__ out,
                          int P) {
    int gid = blockIdx.x * blockDim.x + threadIdx.x;   // (b*NCH + c)*1152 + seg
    if (gid >= BB * NCH * (NPIX / 8)) return;
    int seg = gid % (NPIX / 8);
    int bc  = gid / (NPIX / 8);
    int b = bc / NCH;
    int n0 = seg * 8;
    float o[8] = {0.f, 0.f, 0.f, 0.f, 0.f, 0.f, 0.f, 0.f};
    for (int p = 0; p < P; ++p) {
        ushort8 t = *(const ushort8*)(pacc +
            (((size_t)b * P + p) * NCH + (bc % NCH)) * NPIX + n0);
        #pragma unroll
        for (int e = 0; e < 8; ++e) o[e] += bf2f(t[e]);
    }
    const float* lv = linv + (size_t)b * NPIX + n0;
    const float* xb = x + (size_t)bc * NPIX + n0;
    float* ob = out + (size_t)bc * NPIX + n0;
    #pragma unroll
    for (int e = 0; e < 8; ++e)
        ob[e] = fmaf(lv[e], o[e], xb[e]);
}

// ---------------------------------------------------------------------------
extern "C" void kernel_launch(void* const* d_in, const int* in_sizes, int n_in,
                              void* d_out, int out_size, void* d_ws, size_t ws_size,
                              hipStream_t stream) {
    const float* x      = (const float*)d_in[0];
    const float* w_red  = (const float*)d_in[1];
    const float* b_red  = (const float*)d_in[2];
    const float* w_dil  = (const float*)d_in[3];
    const float* b_dil  = (const float*)d_in[4];
    const float* w_fuse = (const float*)d_in[5];
    const float* b_fuse = (const float*)d_in[6];
    float* out = (float*)d_out;

    // ws: xred f32 | FT bf16 | tok bf16 | tokT bf16 | pl f32 | linv f32 | pacc bf16
    const size_t XRED_N = (size_t)BB * INNER * NPIX;
    const size_t FT_N   = (size_t)64 * TOTPIX;
    const size_t TOK_N  = (size_t)BB * NPIX * NCH;
    const size_t HEAD_B = XRED_N * 4 + (FT_N + 2 * TOK_N) * 2 + TOTPIX * 4;
    int P = 0;
    const int cands[5] = {16, 8, 4, 2, 1};   // KP = 9216/P multiple of 32 for all
    for (int ci = 0; ci < 5; ++ci) {
        int cp = cands[ci];
        size_t need = HEAD_B + (size_t)BB * cp * NPIX * (4 + NCH * 2);
        if (ws_size >= need) { P = cp; break; }
    }
    if (P == 0) return;

    float*  xred = (float*)d_ws;
    ushort* FT   = (ushort*)(xred + XRED_N);
    ushort* tok  = FT + FT_N;
    ushort* tokT = tok + TOK_N;
    float*  pl   = (float*)(tokT + TOK_N);
    float*  linv = pl + (size_t)BB * P * NPIX;
    ushort* pacc = (ushort*)(linv + TOTPIX);

    k_reduce <<<(TOTPIX + 255) / 256, 256, 0, stream>>>(x, w_red, b_red, xred);
    k_feat   <<<3 * TOTPIX / 256, 256, 0, stream>>>(xred, w_dil, b_dil, FT);
    k_fuse   <<<TOTPIX / 64, 256, 0, stream>>>(FT, w_fuse, b_fuse, tok, tokT);
    k_attn   <<<BB * P * (NPIX / 256), 256, 0, stream>>>(tok, tokT, pl, pacc,
                                                         P, NPIX / P);
    k_norm   <<<(TOTPIX + 255) / 256, 256, 0, stream>>>(pl, linv, P);
    k_combine<<<(BB * NCH * (NPIX / 8) + 255) / 256, 256, 0, stream>>>(x, linv, pacc,
                                                                       out, P);
}